// Round 11
// baseline (174.066 us; speedup 1.0000x reference)
//
#include <hip/hip_runtime.h>
#include <hip/hip_bf16.h>
#include <math.h>

// SelfAttention: out = softmax(mask(q k^T)/32) v, q=xWq^T k=xWk^T v=xWv^T
// N=4096 tokens, E=1024. bf16 MFMA compute, fp32 accumulate.
// R11: occupancy over depth. qkv8/qk8 2-deep (64KB LDS -> 2 blocks/CU,
//      4 waves/SIMD); pv4 3-deep (48KB -> 3 blocks/CU, counted vmcnt).

typedef __attribute__((ext_vector_type(8))) __bf16 bf16x8;
typedef __attribute__((ext_vector_type(4))) __bf16 bf16x4;
typedef __attribute__((ext_vector_type(4))) float f32x4;

__device__ __forceinline__ void gload_lds16(const void* g, void* l) {
  __builtin_amdgcn_global_load_lds(
      (__attribute__((address_space(1))) void*)(g),
      (__attribute__((address_space(3))) void*)(l), 16, 0, 0);
}

#define WAITB(N) asm volatile("s_waitcnt vmcnt(" #N ")\ns_barrier" ::: "memory")

// Swizzled ds_read of one bf16x8 fragment at (row r, k-chunk hi).
#define LDS_FRAG(base, r) \
  *(const bf16x8*)((base) + (r) * 32 + (((hi) ^ (((r) >> 1) & 3)) * 8))

#define MM16(mq, AF)                                                        \
  __builtin_amdgcn_s_setprio(1);                                            \
  _Pragma("unroll") for (int m = 0; m < 4; ++m)                             \
    _Pragma("unroll") for (int n = 0; n < 4; ++n)                           \
      acc[(mq) * 4 + m][n] = __builtin_amdgcn_mfma_f32_16x16x32_bf16(       \
          AF[m], bfr[n], acc[(mq) * 4 + m][n], 0, 0, 0);                    \
  __builtin_amdgcn_s_setprio(0);

// ---- 256x256 tile, BK=32, 8 waves (2M x 4N), 2-deep LDS pipeline ----
// Stage t+1 at iter top; WAITB(0) at iter end (full-body cover + TLP).
template <int NT>
__device__ __forceinline__ void g8_loop(const __bf16* __restrict__ A, long lda, long row0,
                                        const __bf16* __restrict__ B, long ldb, long col0,
                                        int kt0, __bf16* sA, __bf16* sB,
                                        f32x4 (&acc)[8][4], int tid) {
  const int lane = tid & 63;
  const int w = tid >> 6;
  const int wr = w >> 2, wc = w & 3;
  const int lo = lane & 15, hi = lane >> 4;

  auto stageA = [&](int buf, int kt) {
#pragma unroll
    for (int j = 0; j < 2; ++j) {
      int p = tid + j * 512;
      int row = p >> 2, cg = (p & 3) ^ ((row >> 1) & 3);
      gload_lds16(A + (row0 + row) * lda + kt * 32 + cg * 8,
                  sA + buf * 8192 + p * 8);
    }
  };
  auto stageB = [&](int buf, int kt) {
#pragma unroll
    for (int j = 0; j < 2; ++j) {
      int p = tid + j * 512;
      int row = p >> 2, cg = (p & 3) ^ ((row >> 1) & 3);
      gload_lds16(B + (col0 + row) * ldb + kt * 32 + cg * 8,
                  sB + buf * 8192 + p * 8);
    }
  };

  stageA(0, kt0); stageB(0, kt0);
  WAITB(0);  // tile0 landed

  for (int t = 0; t < NT; ++t) {
    const int d = t & 1;
    const __bf16* sAc = sA + d * 8192;
    const __bf16* sBc = sB + d * 8192;
    // Issue next tile's loads first (overwrites buf of t-1: reads drained
    // by lgkmcnt before MFMA + end-of-iter barrier, block-wide safe).
    if (t + 1 < NT) { stageA(d ^ 1, kt0 + t + 1); stageB(d ^ 1, kt0 + t + 1); }
    bf16x8 af[4], bfr[4];
#pragma unroll
    for (int m = 0; m < 4; ++m) af[m] = LDS_FRAG(sAc, wr * 128 + m * 16 + lo);
#pragma unroll
    for (int n = 0; n < 4; ++n) bfr[n] = LDS_FRAG(sBc, wc * 64 + n * 16 + lo);
    __builtin_amdgcn_s_barrier();
    MM16(0, af);
    __builtin_amdgcn_s_barrier();
    bf16x8 af2[4];
#pragma unroll
    for (int m = 0; m < 4; ++m) af2[m] = LDS_FRAG(sAc, wr * 128 + 64 + m * 16 + lo);
    __builtin_amdgcn_s_barrier();
    MM16(1, af2);
    WAITB(0);  // t+1 landed; barrier releases buf d for next iter's stage
  }
}

// ---------------- kernels ----------------

// Fused QKV. z=0: q = x Wq^T; z=1: k = x Wk^T; z=2: vT = Wv x^T.
__global__ __launch_bounds__(512) void qkv8(const __bf16* __restrict__ xb,
                                            const __bf16* __restrict__ wq,
                                            const __bf16* __restrict__ wk,
                                            const __bf16* __restrict__ wv,
                                            __bf16* __restrict__ qb,
                                            __bf16* __restrict__ kb,
                                            __bf16* __restrict__ vtb) {
  __shared__ __bf16 sA[2 * 8192];
  __shared__ __bf16 sB[2 * 8192];
  const int raw = blockIdx.x;
  const int wid = (raw & 7) * 24 + (raw >> 3);   // nwg=192, bijective
  const int z = wid >> 6;
  const int r2 = wid & 63;
  const int tid = threadIdx.x;
  const __bf16* A;
  const __bf16* B;
  long row0, col0;
  if (z == 2) {            // A = Wv, B = x  -> vT coalesced
    A = wv; B = xb;
    row0 = (long)(r2 >> 4) * 256;
    col0 = (long)(r2 & 15) * 256;
  } else {
    A = xb; B = (z == 0) ? wq : wk;
    row0 = (long)(r2 >> 2) * 256;
    col0 = (long)(r2 & 3) * 256;
  }
  f32x4 acc[8][4] = {};
  g8_loop<32>(A, 1024, row0, B, 1024, col0, 0, sA, sB, acc, tid);

  const int lane = tid & 63, w = tid >> 6;
  const int wr = w >> 2, wc = w & 3;
  const int lo = lane & 15, hi = lane >> 4;
#pragma unroll
  for (int m = 0; m < 8; ++m)
#pragma unroll
    for (int n = 0; n < 4; ++n)
#pragma unroll
      for (int i = 0; i < 4; ++i) {
        long r = row0 + wr * 128 + m * 16 + hi * 4 + i;
        long c = col0 + wc * 64 + n * 16 + lo;
        __bf16 v = (__bf16)acc[m][n][i];
        if (z == 0)      qb[r * 1024 + c] = v;
        else if (z == 1) kb[r * 1024 + c] = v;
        else             vtb[r * 4096 + c] = v;
      }
}

// sim = q k^T (bf16 out, ld 4096). 1D XCD map.
__global__ __launch_bounds__(512) void qk8(const __bf16* __restrict__ qb,
                                           const __bf16* __restrict__ kb,
                                           __bf16* __restrict__ sim) {
  __shared__ __bf16 sA[2 * 8192];
  __shared__ __bf16 sB[2 * 8192];
  const int raw = blockIdx.x;
  const int wid = (raw & 7) * 32 + (raw >> 3);   // nwg=256, bijective
  const long row0 = (long)(wid >> 4) * 256;
  const long col0 = (long)(wid & 15) * 256;
  const int tid = threadIdx.x;
  f32x4 acc[8][4] = {};
  g8_loop<32>(qb, 1024, row0, kb, 1024, col0, 0, sA, sB, acc, tid);

  const int lane = tid & 63, w = tid >> 6;
  const int wr = w >> 2, wc = w & 3;
  const int lo = lane & 15, hi = lane >> 4;
#pragma unroll
  for (int m = 0; m < 8; ++m)
#pragma unroll
    for (int n = 0; n < 4; ++n)
#pragma unroll
      for (int i = 0; i < 4; ++i) {
        long r = row0 + wr * 128 + m * 16 + hi * 4 + i;
        long c = col0 + wc * 64 + n * 16 + lo;
        sim[r * 4096 + c] = (__bf16)acc[m][n][i];
      }
}

// PV split-K x2: 128x128 tile, 4 waves (2x2 of 64x64), BK=32, NT=64.
// 3-deep LDS (48KB) -> 3 blocks/CU; counted WAITB(4).
__global__ __launch_bounds__(256) void pv4(const __bf16* __restrict__ attn,
                                           const __bf16* __restrict__ vt,
                                           float* __restrict__ out,
                                           float* __restrict__ p1) {
  __shared__ __bf16 sA[3 * 4096];
  __shared__ __bf16 sB[3 * 4096];
  const int raw = blockIdx.x;
  const int wid = (raw & 7) * 64 + (raw >> 3);   // nwg=512, bijective
  const int z = wid >> 8;
  const int r2 = wid & 255;
  const long row0 = (long)(r2 >> 3) * 128;       // token panel [0,32)
  const long col0 = (long)(r2 & 7) * 128;        // feature panel [0,8)
  float* C = z ? p1 : out;
  const int kt0 = z * 64;
  const int tid = threadIdx.x;
  const int lane = tid & 63, w = tid >> 6;
  const int wr = w >> 1, wc = w & 1;
  const int lo = lane & 15, hi = lane >> 4;
  constexpr int NT = 64;

  auto stageA = [&](int buf, int kt) {
#pragma unroll
    for (int j = 0; j < 2; ++j) {
      int p = tid + j * 256;
      int row = p >> 2, cg = (p & 3) ^ ((row >> 1) & 3);
      gload_lds16(attn + (row0 + row) * 4096 + kt * 32 + cg * 8,
                  sA + buf * 4096 + p * 8);
    }
  };
  auto stageB = [&](int buf, int kt) {
#pragma unroll
    for (int j = 0; j < 2; ++j) {
      int p = tid + j * 256;
      int row = p >> 2, cg = (p & 3) ^ ((row >> 1) & 3);
      gload_lds16(vt + (col0 + row) * 4096 + kt * 32 + cg * 8,
                  sB + buf * 4096 + p * 8);
    }
  };

  f32x4 acc[4][4] = {};
  stageA(0, kt0); stageB(0, kt0);
  stageA(1, kt0 + 1); stageB(1, kt0 + 1);
  WAITB(4);  // tile0 landed; tile1 in flight

  int d = 0;
  for (int t = 0; t < NT; ++t) {
    const __bf16* sAc = sA + d * 4096;
    const __bf16* sBc = sB + d * 4096;
    int s = d + 2; if (s >= 3) s -= 3;   // buffer of tile t-1: free
    bf16x8 af[4], bfr[4];
#pragma unroll
    for (int m = 0; m < 4; ++m) af[m] = LDS_FRAG(sAc, wr * 64 + m * 16 + lo);
#pragma unroll
    for (int n = 0; n < 4; ++n) bfr[n] = LDS_FRAG(sBc, wc * 64 + n * 16 + lo);
    if (t + 2 < NT) { stageA(s, kt0 + t + 2); stageB(s, kt0 + t + 2); }
    __builtin_amdgcn_s_barrier();
    __builtin_amdgcn_s_setprio(1);
#pragma unroll
    for (int m = 0; m < 4; ++m)
#pragma unroll
      for (int n = 0; n < 4; ++n)
        acc[m][n] = __builtin_amdgcn_mfma_f32_16x16x32_bf16(af[m], bfr[n], acc[m][n], 0, 0, 0);
    __builtin_amdgcn_s_setprio(0);
    if (t + 2 < NT) { WAITB(4); } else { WAITB(0); }
    if (++d == 3) d = 0;
  }

#pragma unroll
  for (int m = 0; m < 4; ++m)
#pragma unroll
    for (int n = 0; n < 4; ++n)
#pragma unroll
      for (int i = 0; i < 4; ++i) {
        long r = row0 + wr * 64 + m * 16 + hi * 4 + i;
        long c = col0 + wc * 64 + n * 16 + lo;
        C[r * 1024 + c] = acc[m][n][i];
      }
}

// out += p1
__global__ __launch_bounds__(256) void reduce_add2(float* __restrict__ out,
                                                   const float* __restrict__ p1) {
  int i = blockIdx.x * 256 + threadIdx.x;  // 1,048,576 float4s
  float4 a = ((const float4*)out)[i];
  float4 b = ((const float4*)p1)[i];
  a.x += b.x; a.y += b.y; a.z += b.z; a.w += b.w;
  ((float4*)out)[i] = a;
}

// One block per row of bf16 sim (ld 4096): mask, stable softmax of row/32,
// write normalized attn bf16 IN-PLACE.
__global__ __launch_bounds__(256) void softmax_rows(__bf16* __restrict__ sim,
                                                    const int* __restrict__ mask) {
  const int row = blockIdx.x;
  __bf16* rp = sim + (size_t)row * 4096;
  const int4* mrow = (const int4*)(mask + (size_t)row * 4096);
  const int tid = threadIdx.x;

  float vals[16];
  float lmax = -INFINITY;
#pragma unroll
  for (int j = 0; j < 2; ++j) {
    bf16x8 s = ((const bf16x8*)rp)[tid + 256 * j];
    int4 m0 = mrow[(tid + 256 * j) * 2];
    int4 m1 = mrow[(tid + 256 * j) * 2 + 1];
    float f[8];
#pragma unroll
    for (int e = 0; e < 8; ++e) f[e] = (float)s[e];
    f[0] = m0.x ? f[0] : -1e20f;  f[1] = m0.y ? f[1] : -1e20f;
    f[2] = m0.z ? f[2] : -1e20f;  f[3] = m0.w ? f[3] : -1e20f;
    f[4] = m1.x ? f[4] : -1e20f;  f[5] = m1.y ? f[5] : -1e20f;
    f[6] = m1.z ? f[6] : -1e20f;  f[7] = m1.w ? f[7] : -1e20f;
#pragma unroll
    for (int e = 0; e < 8; ++e) {
      vals[8 * j + e] = f[e];
      lmax = fmaxf(lmax, f[e]);
    }
  }
#pragma unroll
  for (int off = 32; off; off >>= 1) lmax = fmaxf(lmax, __shfl_xor(lmax, off));
  __shared__ float red[4];
  __shared__ float bro[2];
  if ((tid & 63) == 0) red[tid >> 6] = lmax;
  __syncthreads();
  if (tid == 0) bro[0] = fmaxf(fmaxf(red[0], red[1]), fmaxf(red[2], red[3]));
  __syncthreads();
  const float m = bro[0];

  float e[16];
  float lsum = 0.f;
#pragma unroll
  for (int j = 0; j < 16; ++j) {
    e[j] = __expf((vals[j] - m) * 0.03125f);
    lsum += e[j];
  }
#pragma unroll
  for (int off = 32; off; off >>= 1) lsum += __shfl_xor(lsum, off);
  if ((tid & 63) == 0) red[tid >> 6] = lsum;
  __syncthreads();
  if (tid == 0) bro[1] = red[0] + red[1] + red[2] + red[3];
  __syncthreads();
  const float inv = 1.0f / bro[1];

#pragma unroll
  for (int j = 0; j < 2; ++j) {
    bf16x8 o;
#pragma unroll
    for (int q = 0; q < 8; ++q) o[q] = (__bf16)(e[8 * j + q] * inv);
    ((bf16x8*)rp)[tid + 256 * j] = o;
  }
}

// Converts x, Wq, Wk, Wv to bf16.
__global__ __launch_bounds__(256) void cvt_all(const float* __restrict__ x,
                                               const float* __restrict__ wq,
                                               const float* __restrict__ wk,
                                               const float* __restrict__ wv,
                                               __bf16* __restrict__ xb,
                                               __bf16* __restrict__ wqb,
                                               __bf16* __restrict__ wkb,
                                               __bf16* __restrict__ wvb) {
  int b = blockIdx.x;
  const float* in;
  __bf16* out;
  int base;
  if (b < 4096)      { in = x;  out = xb;  base = b; }
  else if (b < 5120) { in = wq; out = wqb; base = b - 4096; }
  else if (b < 6144) { in = wk; out = wkb; base = b - 5120; }
  else               { in = wv; out = wvb; base = b - 6144; }
  int i = base * 256 + threadIdx.x;
  float4 f = ((const float4*)in)[i];
  bf16x4 o;
  o[0] = (__bf16)f.x; o[1] = (__bf16)f.y; o[2] = (__bf16)f.z; o[3] = (__bf16)f.w;
  ((bf16x4*)out)[i] = o;
}

extern "C" void kernel_launch(void* const* d_in, const int* in_sizes, int n_in,
                              void* d_out, int out_size, void* d_ws, size_t ws_size,
                              hipStream_t stream) {
  const float* x = (const float*)d_in[0];
  const int* mask = (const int*)d_in[1];
  const float* Wq = (const float*)d_in[2];
  const float* Wk = (const float*)d_in[3];
  const float* Wv = (const float*)d_in[4];
  float* out = (float*)d_out;

  // Workspace layout (70 MB):
  // [0,8M)   vT bf16    [8,16M)  x bf16
  // [16,18M) Wq bf16    [18,20M) Wk bf16   [20,22M) Wv bf16
  // [22,30M) q bf16     [30,38M) k bf16
  // [38,70M) sim bf16 (attn in-place after softmax, ld 4096)
  // PV-time (x,W dead): p1 [8,24M)
  char* ws = (char*)d_ws;
  __bf16* vtb = (__bf16*)(ws);
  __bf16* xb  = (__bf16*)(ws + (8ull << 20));
  __bf16* wqb = (__bf16*)(ws + (16ull << 20));
  __bf16* wkb = (__bf16*)(ws + (18ull << 20));
  __bf16* wvb = (__bf16*)(ws + (20ull << 20));
  __bf16* qb  = (__bf16*)(ws + (22ull << 20));
  __bf16* kb  = (__bf16*)(ws + (30ull << 20));
  __bf16* sim = (__bf16*)(ws + (38ull << 20));
  float*  p1  = (float*)(ws + (8ull << 20));

  cvt_all<<<7168, 256, 0, stream>>>(x, Wq, Wk, Wv, xb, wqb, wkb, wvb);

  // q, k, vT: 192 blocks of 256^2 (2 blocks/CU now)
  qkv8<<<192, 512, 0, stream>>>(xb, wqb, wkb, wvb, qb, kb, vtb);
  // sim = q k^T (4096x4096): 256 blocks (2 blocks/CU now)
  qk8<<<256, 512, 0, stream>>>(qb, kb, sim);
  // masked stable softmax, normalized attn bf16 in-place
  softmax_rows<<<4096, 256, 0, stream>>>(sim, mask);
  // out = attn vT^T: split-K x2, 512 blocks (3 blocks/CU now)
  pv4<<<512, 256, 0, stream>>>(sim, vtb, out, p1);
  reduce_add2<<<4096, 256, 0, stream>>>(out, p1);
}

// Round 12
// 154.606 us; speedup vs baseline: 1.1259x; 1.1259x over previous
//
#include <hip/hip_runtime.h>
#include <hip/hip_bf16.h>
#include <math.h>

// SelfAttention: out = softmax(mask(q k^T)/32) v, q=xWq^T k=xWk^T v=xWv^T
// N=4096 tokens, E=1024. bf16 MFMA compute, fp32 accumulate.
// R12: m201-style 4-phase BK=64 schedule for qkv8/qk8 (per-phase 1-half
//      staging into read-certified slots, WAITB(6) once per K-tile);
//      pv4/softmax/cvt/reduce = R10 (best known).

typedef __attribute__((ext_vector_type(8))) __bf16 bf16x8;
typedef __attribute__((ext_vector_type(4))) __bf16 bf16x4;
typedef __attribute__((ext_vector_type(4))) float f32x4;

__device__ __forceinline__ void gload_lds16(const void* g, void* l) {
  __builtin_amdgcn_global_load_lds(
      (__attribute__((address_space(1))) void*)(g),
      (__attribute__((address_space(3))) void*)(l), 16, 0, 0);
}

#define WAITB(N) asm volatile("s_waitcnt vmcnt(" #N ")\ns_barrier" ::: "memory")
#define BAR()    asm volatile("s_barrier" ::: "memory")
#define MFMA_(a, b, c) __builtin_amdgcn_mfma_f32_16x16x32_bf16(a, b, c, 0, 0, 0)

// BK=64 swizzled frag read (R5-proven 0-conflict): row r, kk in {0,32}.
#define FRAG64(base, r, kk) \
  *(const bf16x8*)((base) + (r) * 64 + (((((kk) >> 3) + hi) ^ ((r) & 7)) * 8))

// ---- m201-style 4-phase loop: 256x256 tile, BK=64, 8 waves (2M x 4N) ----
// LDS: 2 dbuf x 256x64 per matrix = 128KB total. Per K-tile:
// P1{readA(m0-3)+B(n0-1); stage A(t+1).h2; BAR; MFMA q00; BAR}
// P2{readB(n2-3); stage A(t+2).h1; BAR; MFMA q01; BAR}
// P3{readA(m4-7); stage B(t+2).h1; BAR; MFMA q10; BAR}
// P4{stage B(t+2).h2; BAR; MFMA q11; WAITB(6)}
// Halves: A.h1 = rows {0-63,128-191} (read P1), A.h2 = +64 (P3);
//         B.h1 = rows == [0,32) mod 64 (P1), B.h2 = +32 (P2).
template <int NT>
__device__ __forceinline__ void g8m(const __bf16* __restrict__ A, long lda, long row0,
                                    const __bf16* __restrict__ B, long ldb, long col0,
                                    __bf16* sA, __bf16* sB,
                                    f32x4 (&acc)[8][4], int tid) {
  const int lane = tid & 63, w = tid >> 6;
  const int wr = w >> 2, wc = w & 3;
  const int lo = lane & 15, hi = lane >> 4;

  auto stA = [&](int buf, int t, int h) {
#pragma unroll
    for (int j = 0; j < 2; ++j) {
      int p = tid + j * 512;                       // [0,1024) chunk in half
      int rp = p >> 3, c = p & 7;
      int arow = rp + (j ? 64 : 0) + (h ? 64 : 0); // rp>=64 iff j==1
      int cg = c ^ (arow & 7);
      gload_lds16(A + (row0 + arow) * lda + t * 64 + cg * 8,
                  sA + buf * 16384 + arow * 64 + c * 8);
    }
  };
  auto stB = [&](int buf, int t, int h) {
#pragma unroll
    for (int j = 0; j < 2; ++j) {
      int p = tid + j * 512;
      int rp = p >> 3, c = p & 7;
      int arow = ((rp >> 5) << 6) + (rp & 31) + (h ? 32 : 0);
      int cg = c ^ (arow & 7);
      gload_lds16(B + (col0 + arow) * ldb + t * 64 + cg * 8,
                  sB + buf * 16384 + arow * 64 + c * 8);
    }
  };

  // Prologue: tile0 fully (8 loads) + tile1 {A.h1, B.h1, B.h2} (6 loads).
  stA(0, 0, 0); stA(0, 0, 1); stB(0, 0, 0); stB(0, 0, 1);
  stA(1, 1, 0); stB(1, 1, 0); stB(1, 1, 1);
  WAITB(6);  // tile0 landed; 3 halves of tile1 in flight

  for (int t = 0; t < NT; ++t) {
    const int bf = t & 1;
    const __bf16* sAc = sA + bf * 16384;
    const __bf16* sBc = sB + bf * 16384;
    bf16x8 a4[8], b01[4], b23[4];
    // ---- P1: quad (m0-3, n0-1)
#pragma unroll
    for (int m = 0; m < 4; ++m) {
      a4[m * 2]     = FRAG64(sAc, wr * 128 + m * 16 + lo, 0);
      a4[m * 2 + 1] = FRAG64(sAc, wr * 128 + m * 16 + lo, 32);
    }
#pragma unroll
    for (int n = 0; n < 2; ++n) {
      b01[n * 2]     = FRAG64(sBc, wc * 64 + n * 16 + lo, 0);
      b01[n * 2 + 1] = FRAG64(sBc, wc * 64 + n * 16 + lo, 32);
    }
    if (t + 1 < NT) stA(bf ^ 1, t + 1, 1);
    BAR();
    __builtin_amdgcn_s_setprio(1);
#pragma unroll
    for (int m = 0; m < 4; ++m)
#pragma unroll
      for (int n = 0; n < 2; ++n) {
        acc[m][n] = MFMA_(a4[m * 2], b01[n * 2], acc[m][n]);
        acc[m][n] = MFMA_(a4[m * 2 + 1], b01[n * 2 + 1], acc[m][n]);
      }
    __builtin_amdgcn_s_setprio(0);
    BAR();
    // ---- P2: quad (m0-3, n2-3)
#pragma unroll
    for (int n = 0; n < 2; ++n) {
      b23[n * 2]     = FRAG64(sBc, wc * 64 + (n + 2) * 16 + lo, 0);
      b23[n * 2 + 1] = FRAG64(sBc, wc * 64 + (n + 2) * 16 + lo, 32);
    }
    if (t + 2 < NT) stA(bf, t + 2, 0);
    BAR();
    __builtin_amdgcn_s_setprio(1);
#pragma unroll
    for (int m = 0; m < 4; ++m)
#pragma unroll
      for (int n = 0; n < 2; ++n) {
        acc[m][n + 2] = MFMA_(a4[m * 2], b23[n * 2], acc[m][n + 2]);
        acc[m][n + 2] = MFMA_(a4[m * 2 + 1], b23[n * 2 + 1], acc[m][n + 2]);
      }
    __builtin_amdgcn_s_setprio(0);
    BAR();
    // ---- P3: quad (m4-7, n0-1); a4 overwritten with m4-7
#pragma unroll
    for (int m = 0; m < 4; ++m) {
      a4[m * 2]     = FRAG64(sAc, wr * 128 + 64 + m * 16 + lo, 0);
      a4[m * 2 + 1] = FRAG64(sAc, wr * 128 + 64 + m * 16 + lo, 32);
    }
    if (t + 2 < NT) stB(bf, t + 2, 0);
    BAR();
    __builtin_amdgcn_s_setprio(1);
#pragma unroll
    for (int m = 0; m < 4; ++m)
#pragma unroll
      for (int n = 0; n < 2; ++n) {
        acc[4 + m][n] = MFMA_(a4[m * 2], b01[n * 2], acc[4 + m][n]);
        acc[4 + m][n] = MFMA_(a4[m * 2 + 1], b01[n * 2 + 1], acc[4 + m][n]);
      }
    __builtin_amdgcn_s_setprio(0);
    BAR();
    // ---- P4: quad (m4-7, n2-3)
    if (t + 2 < NT) stB(bf, t + 2, 1);
    BAR();
    __builtin_amdgcn_s_setprio(1);
#pragma unroll
    for (int m = 0; m < 4; ++m)
#pragma unroll
      for (int n = 0; n < 2; ++n) {
        acc[4 + m][n + 2] = MFMA_(a4[m * 2], b23[n * 2], acc[4 + m][n + 2]);
        acc[4 + m][n + 2] = MFMA_(a4[m * 2 + 1], b23[n * 2 + 1], acc[4 + m][n + 2]);
      }
    __builtin_amdgcn_s_setprio(0);
    if (t + 2 < NT) { WAITB(6); }   // retire tile t+1's 4 halves exactly
    else            { WAITB(0); }   // tail drain
  }
}

// ---------------- kernels ----------------

// Fused QKV. z=0: q = x Wq^T; z=1: k = x Wk^T; z=2: vT = Wv x^T.
__global__ __launch_bounds__(512) void qkv8(const __bf16* __restrict__ xb,
                                            const __bf16* __restrict__ wq,
                                            const __bf16* __restrict__ wk,
                                            const __bf16* __restrict__ wv,
                                            __bf16* __restrict__ qb,
                                            __bf16* __restrict__ kb,
                                            __bf16* __restrict__ vtb) {
  __shared__ __bf16 sA[2 * 16384];
  __shared__ __bf16 sB[2 * 16384];
  const int raw = blockIdx.x;
  const int wid = (raw & 7) * 24 + (raw >> 3);   // nwg=192, bijective
  const int z = wid >> 6;
  const int r2 = wid & 63;
  const int tid = threadIdx.x;
  const __bf16* A;
  const __bf16* B;
  long row0, col0;
  if (z == 2) {            // A = Wv, B = x  -> vT coalesced
    A = wv; B = xb;
    row0 = (long)(r2 >> 4) * 256;
    col0 = (long)(r2 & 15) * 256;
  } else {
    A = xb; B = (z == 0) ? wq : wk;
    row0 = (long)(r2 >> 2) * 256;
    col0 = (long)(r2 & 3) * 256;
  }
  f32x4 acc[8][4] = {};
  g8m<16>(A, 1024, row0, B, 1024, col0, sA, sB, acc, tid);

  const int lane = tid & 63, w = tid >> 6;
  const int wr = w >> 2, wc = w & 3;
  const int lo = lane & 15, hi = lane >> 4;
#pragma unroll
  for (int m = 0; m < 8; ++m)
#pragma unroll
    for (int n = 0; n < 4; ++n)
#pragma unroll
      for (int i = 0; i < 4; ++i) {
        long r = row0 + wr * 128 + m * 16 + hi * 4 + i;
        long c = col0 + wc * 64 + n * 16 + lo;
        __bf16 v = (__bf16)acc[m][n][i];
        if (z == 0)      qb[r * 1024 + c] = v;
        else if (z == 1) kb[r * 1024 + c] = v;
        else             vtb[r * 4096 + c] = v;
      }
}

// sim = q k^T (bf16 out, ld 4096). 1D XCD map.
__global__ __launch_bounds__(512) void qk8(const __bf16* __restrict__ qb,
                                           const __bf16* __restrict__ kb,
                                           __bf16* __restrict__ sim) {
  __shared__ __bf16 sA[2 * 16384];
  __shared__ __bf16 sB[2 * 16384];
  const int raw = blockIdx.x;
  const int wid = (raw & 7) * 32 + (raw >> 3);   // nwg=256, bijective
  const long row0 = (long)(wid >> 4) * 256;
  const long col0 = (long)(wid & 15) * 256;
  const int tid = threadIdx.x;
  f32x4 acc[8][4] = {};
  g8m<16>(qb, 1024, row0, kb, 1024, col0, sA, sB, acc, tid);

  const int lane = tid & 63, w = tid >> 6;
  const int wr = w >> 2, wc = w & 3;
  const int lo = lane & 15, hi = lane >> 4;
#pragma unroll
  for (int m = 0; m < 8; ++m)
#pragma unroll
    for (int n = 0; n < 4; ++n)
#pragma unroll
      for (int i = 0; i < 4; ++i) {
        long r = row0 + wr * 128 + m * 16 + hi * 4 + i;
        long c = col0 + wc * 64 + n * 16 + lo;
        sim[r * 4096 + c] = (__bf16)acc[m][n][i];
      }
}

// ---- R10 pv4: split-K x2, 128x128 tile, 4 waves, BK=32, 4-deep counted ----
#define LDS_FRAG32(base, r) \
  *(const bf16x8*)((base) + (r) * 32 + (((hi) ^ (((r) >> 1) & 3)) * 8))

__global__ __launch_bounds__(256) void pv4(const __bf16* __restrict__ attn,
                                           const __bf16* __restrict__ vt,
                                           float* __restrict__ out,
                                           float* __restrict__ p1) {
  __shared__ __bf16 sA[4 * 4096];
  __shared__ __bf16 sB[4 * 4096];
  const int raw = blockIdx.x;
  const int wid = (raw & 7) * 64 + (raw >> 3);   // nwg=512, bijective
  const int z = wid >> 8;
  const int r2 = wid & 255;
  const long row0 = (long)(r2 >> 3) * 128;
  const long col0 = (long)(r2 & 7) * 128;
  float* C = z ? p1 : out;
  const int kt0 = z * 64;
  const int tid = threadIdx.x;
  const int lane = tid & 63, w = tid >> 6;
  const int wr = w >> 1, wc = w & 1;
  const int lo = lane & 15, hi = lane >> 4;
  constexpr int NT = 64;

  auto stageA = [&](int buf, int kt) {
#pragma unroll
    for (int j = 0; j < 2; ++j) {
      int p = tid + j * 256;
      int row = p >> 2, cg = (p & 3) ^ ((row >> 1) & 3);
      gload_lds16(attn + (row0 + row) * 4096 + kt * 32 + cg * 8,
                  sA + buf * 4096 + p * 8);
    }
  };
  auto stageB = [&](int buf, int kt) {
#pragma unroll
    for (int j = 0; j < 2; ++j) {
      int p = tid + j * 256;
      int row = p >> 2, cg = (p & 3) ^ ((row >> 1) & 3);
      gload_lds16(vt + (col0 + row) * 4096 + kt * 32 + cg * 8,
                  sB + buf * 4096 + p * 8);
    }
  };

  f32x4 acc[4][4] = {};
#pragma unroll
  for (int t = 0; t < 3; ++t) { stageA(t, kt0 + t); stageB(t, kt0 + t); }
  WAITB(8);

  for (int t = 0; t < NT; ++t) {
    const int d = t & 3;
    const __bf16* sAc = sA + d * 4096;
    const __bf16* sBc = sB + d * 4096;
    const int s = (t + 3) & 3;
    bf16x8 af[4], bfr[4];
#pragma unroll
    for (int m = 0; m < 4; ++m) af[m] = LDS_FRAG32(sAc, wr * 64 + m * 16 + lo);
#pragma unroll
    for (int n = 0; n < 4; ++n) bfr[n] = LDS_FRAG32(sBc, wc * 64 + n * 16 + lo);
    if (t + 3 < NT) { stageA(s, kt0 + t + 3); stageB(s, kt0 + t + 3); }
    __builtin_amdgcn_s_barrier();
    __builtin_amdgcn_s_setprio(1);
#pragma unroll
    for (int m = 0; m < 4; ++m)
#pragma unroll
      for (int n = 0; n < 4; ++n)
        acc[m][n] = MFMA_(af[m], bfr[n], acc[m][n]);
    __builtin_amdgcn_s_setprio(0);
    if (t + 3 < NT)      { WAITB(8); }
    else if (t + 2 < NT) { WAITB(4); }
    else                 { WAITB(0); }
  }

#pragma unroll
  for (int m = 0; m < 4; ++m)
#pragma unroll
    for (int n = 0; n < 4; ++n)
#pragma unroll
      for (int i = 0; i < 4; ++i) {
        long r = row0 + wr * 64 + m * 16 + hi * 4 + i;
        long c = col0 + wc * 64 + n * 16 + lo;
        C[r * 1024 + c] = acc[m][n][i];
      }
}

// out += p1
__global__ __launch_bounds__(256) void reduce_add2(float* __restrict__ out,
                                                   const float* __restrict__ p1) {
  int i = blockIdx.x * 256 + threadIdx.x;
  float4 a = ((const float4*)out)[i];
  float4 b = ((const float4*)p1)[i];
  a.x += b.x; a.y += b.y; a.z += b.z; a.w += b.w;
  ((float4*)out)[i] = a;
}

// One block per row of bf16 sim (ld 4096): mask, stable softmax of row/32.
__global__ __launch_bounds__(256) void softmax_rows(__bf16* __restrict__ sim,
                                                    const int* __restrict__ mask) {
  const int row = blockIdx.x;
  __bf16* rp = sim + (size_t)row * 4096;
  const int4* mrow = (const int4*)(mask + (size_t)row * 4096);
  const int tid = threadIdx.x;

  float vals[16];
  float lmax = -INFINITY;
#pragma unroll
  for (int j = 0; j < 2; ++j) {
    bf16x8 s = ((const bf16x8*)rp)[tid + 256 * j];
    int4 m0 = mrow[(tid + 256 * j) * 2];
    int4 m1 = mrow[(tid + 256 * j) * 2 + 1];
    float f[8];
#pragma unroll
    for (int e = 0; e < 8; ++e) f[e] = (float)s[e];
    f[0] = m0.x ? f[0] : -1e20f;  f[1] = m0.y ? f[1] : -1e20f;
    f[2] = m0.z ? f[2] : -1e20f;  f[3] = m0.w ? f[3] : -1e20f;
    f[4] = m1.x ? f[4] : -1e20f;  f[5] = m1.y ? f[5] : -1e20f;
    f[6] = m1.z ? f[6] : -1e20f;  f[7] = m1.w ? f[7] : -1e20f;
#pragma unroll
    for (int e = 0; e < 8; ++e) {
      vals[8 * j + e] = f[e];
      lmax = fmaxf(lmax, f[e]);
    }
  }
#pragma unroll
  for (int off = 32; off; off >>= 1) lmax = fmaxf(lmax, __shfl_xor(lmax, off));
  __shared__ float red[4];
  __shared__ float bro[2];
  if ((tid & 63) == 0) red[tid >> 6] = lmax;
  __syncthreads();
  if (tid == 0) bro[0] = fmaxf(fmaxf(red[0], red[1]), fmaxf(red[2], red[3]));
  __syncthreads();
  const float m = bro[0];

  float e[16];
  float lsum = 0.f;
#pragma unroll
  for (int j = 0; j < 16; ++j) {
    e[j] = __expf((vals[j] - m) * 0.03125f);
    lsum += e[j];
  }
#pragma unroll
  for (int off = 32; off; off >>= 1) lsum += __shfl_xor(lsum, off);
  if ((tid & 63) == 0) red[tid >> 6] = lsum;
  __syncthreads();
  if (tid == 0) bro[1] = red[0] + red[1] + red[2] + red[3];
  __syncthreads();
  const float inv = 1.0f / bro[1];

#pragma unroll
  for (int j = 0; j < 2; ++j) {
    bf16x8 o;
#pragma unroll
    for (int q = 0; q < 8; ++q) o[q] = (__bf16)(e[8 * j + q] * inv);
    ((bf16x8*)rp)[tid + 256 * j] = o;
  }
}

// Converts x, Wq, Wk, Wv to bf16.
__global__ __launch_bounds__(256) void cvt_all(const float* __restrict__ x,
                                               const float* __restrict__ wq,
                                               const float* __restrict__ wk,
                                               const float* __restrict__ wv,
                                               __bf16* __restrict__ xb,
                                               __bf16* __restrict__ wqb,
                                               __bf16* __restrict__ wkb,
                                               __bf16* __restrict__ wvb) {
  int b = blockIdx.x;
  const float* in;
  __bf16* out;
  int base;
  if (b < 4096)      { in = x;  out = xb;  base = b; }
  else if (b < 5120) { in = wq; out = wqb; base = b - 4096; }
  else if (b < 6144) { in = wk; out = wkb; base = b - 5120; }
  else               { in = wv; out = wvb; base = b - 6144; }
  int i = base * 256 + threadIdx.x;
  float4 f = ((const float4*)in)[i];
  bf16x4 o;
  o[0] = (__bf16)f.x; o[1] = (__bf16)f.y; o[2] = (__bf16)f.z; o[3] = (__bf16)f.w;
  ((bf16x4*)out)[i] = o;
}

extern "C" void kernel_launch(void* const* d_in, const int* in_sizes, int n_in,
                              void* d_out, int out_size, void* d_ws, size_t ws_size,
                              hipStream_t stream) {
  const float* x = (const float*)d_in[0];
  const int* mask = (const int*)d_in[1];
  const float* Wq = (const float*)d_in[2];
  const float* Wk = (const float*)d_in[3];
  const float* Wv = (const float*)d_in[4];
  float* out = (float*)d_out;

  // Workspace layout (70 MB):
  // [0,8M)   vT bf16    [8,16M)  x bf16
  // [16,18M) Wq bf16    [18,20M) Wk bf16   [20,22M) Wv bf16
  // [22,30M) q bf16     [30,38M) k bf16
  // [38,70M) sim bf16 (attn in-place after softmax, ld 4096)
  // PV-time (x,W dead): p1 [8,24M)
  char* ws = (char*)d_ws;
  __bf16* vtb = (__bf16*)(ws);
  __bf16* xb  = (__bf16*)(ws + (8ull << 20));
  __bf16* wqb = (__bf16*)(ws + (16ull << 20));
  __bf16* wkb = (__bf16*)(ws + (18ull << 20));
  __bf16* wvb = (__bf16*)(ws + (20ull << 20));
  __bf16* qb  = (__bf16*)(ws + (22ull << 20));
  __bf16* kb  = (__bf16*)(ws + (30ull << 20));
  __bf16* sim = (__bf16*)(ws + (38ull << 20));
  float*  p1  = (float*)(ws + (8ull << 20));

  cvt_all<<<7168, 256, 0, stream>>>(x, Wq, Wk, Wv, xb, wqb, wkb, wvb);

  // q, k, vT: 192 blocks of 256^2, 4-phase schedule
  qkv8<<<192, 512, 0, stream>>>(xb, wqb, wkb, wvb, qb, kb, vtb);
  // sim = q k^T (4096x4096): 256 blocks, 4-phase schedule
  qk8<<<256, 512, 0, stream>>>(qb, kb, sim);
  // masked stable softmax, normalized attn bf16 in-place
  softmax_rows<<<4096, 256, 0, stream>>>(sim, mask);
  // out = attn vT^T: split-K x2, 512 blocks (R10 config)
  pv4<<<512, 256, 0, stream>>>(sim, vtb, out, p1);
  reduce_add2<<<4096, 256, 0, stream>>>(out, p1);
}

// Round 13
// 152.692 us; speedup vs baseline: 1.1400x; 1.0125x over previous
//
#include <hip/hip_runtime.h>
#include <hip/hip_bf16.h>
#include <math.h>

// SelfAttention: out = softmax(mask(q k^T)/32) v, q=xWq^T k=xWk^T v=xWv^T
// N=4096 tokens, E=1024. bf16 MFMA compute, fp32 accumulate.
// R13: barrier-minimal tile loop. One counted WAITB per K-tile, NO mid-tile
//      barriers: {12 ds_reads | stage(t+3) | 32 MFMA} is a single fence-free
//      window (compiler fine-lgkmcnt + wave drift provide the overlap).
//      Safety: stage target (t+3)&3 == (t-1)&3 is read-complete by the
//      tile-end barrier; read buffer t&3 is write-complete by counted vmcnt.

typedef __attribute__((ext_vector_type(8))) __bf16 bf16x8;
typedef __attribute__((ext_vector_type(4))) __bf16 bf16x4;
typedef __attribute__((ext_vector_type(4))) float f32x4;

__device__ __forceinline__ void gload_lds16(const void* g, void* l) {
  __builtin_amdgcn_global_load_lds(
      (__attribute__((address_space(1))) void*)(g),
      (__attribute__((address_space(3))) void*)(l), 16, 0, 0);
}

#define WAITB(N) asm volatile("s_waitcnt vmcnt(" #N ")\ns_barrier" ::: "memory")
#define MFMA_(a, b, c) __builtin_amdgcn_mfma_f32_16x16x32_bf16(a, b, c, 0, 0, 0)

// Swizzled ds_read of one bf16x8 fragment at (row r, k-chunk hi). BK=32,
// window = 4*(r&1) + (hi ^ ((r>>1)&3)): 8 balanced windows, 2 lanes each.
#define LDS_FRAG(base, r) \
  *(const bf16x8*)((base) + (r) * 32 + (((hi) ^ (((r) >> 1) & 3)) * 8))

// ---- 256x256 tile, BK=32, 8 waves (2M x 4N), 4-deep LDS, 1 barrier/tile ----
template <int NT>
__device__ __forceinline__ void g8_loop(const __bf16* __restrict__ A, long lda, long row0,
                                        const __bf16* __restrict__ B, long ldb, long col0,
                                        int kt0, __bf16* sA, __bf16* sB,
                                        f32x4 (&acc)[8][4], int tid) {
  const int lane = tid & 63;
  const int w = tid >> 6;
  const int wr = w >> 2, wc = w & 3;
  const int lo = lane & 15, hi = lane >> 4;

  auto stageA = [&](int buf, int kt) {
#pragma unroll
    for (int j = 0; j < 2; ++j) {
      int p = tid + j * 512;
      int row = p >> 2, cg = (p & 3) ^ ((row >> 1) & 3);
      gload_lds16(A + (row0 + row) * lda + kt * 32 + cg * 8,
                  sA + buf * 8192 + p * 8);
    }
  };
  auto stageB = [&](int buf, int kt) {
#pragma unroll
    for (int j = 0; j < 2; ++j) {
      int p = tid + j * 512;
      int row = p >> 2, cg = (p & 3) ^ ((row >> 1) & 3);
      gload_lds16(B + (col0 + row) * ldb + kt * 32 + cg * 8,
                  sB + buf * 8192 + p * 8);
    }
  };

#pragma unroll
  for (int t = 0; t < 3; ++t) { stageA(t, kt0 + t); stageB(t, kt0 + t); }
  WAITB(8);  // tile0 landed; tiles 1,2 in flight

  for (int t = 0; t < NT; ++t) {
    const int d = t & 3;
    const __bf16* sAc = sA + d * 8192;
    const __bf16* sBc = sB + d * 8192;
    const int s = (t + 3) & 3;   // == (t-1)&3: read-complete via tile-end bar
    bf16x8 af[4], af2[4], bfr[4];
#pragma unroll
    for (int m = 0; m < 4; ++m) af[m] = LDS_FRAG(sAc, wr * 128 + m * 16 + lo);
#pragma unroll
    for (int n = 0; n < 4; ++n) bfr[n] = LDS_FRAG(sBc, wc * 64 + n * 16 + lo);
#pragma unroll
    for (int m = 0; m < 4; ++m) af2[m] = LDS_FRAG(sAc, wr * 128 + 64 + m * 16 + lo);
    if (t + 3 < NT) { stageA(s, kt0 + t + 3); stageB(s, kt0 + t + 3); }
    // No barrier: compiler interleaves lgkmcnt-gated MFMAs with the reads.
    __builtin_amdgcn_s_setprio(1);
#pragma unroll
    for (int m = 0; m < 4; ++m)
#pragma unroll
      for (int n = 0; n < 4; ++n)
        acc[m][n] = MFMA_(af[m], bfr[n], acc[m][n]);
#pragma unroll
    for (int m = 0; m < 4; ++m)
#pragma unroll
      for (int n = 0; n < 4; ++n)
        acc[4 + m][n] = MFMA_(af2[m], bfr[n], acc[4 + m][n]);
    __builtin_amdgcn_s_setprio(0);
    if (t + 3 < NT)      { WAITB(8); }
    else if (t + 2 < NT) { WAITB(4); }
    else                 { WAITB(0); }
  }
}

// ---------------- kernels ----------------

// Fused QKV. z=0: q = x Wq^T; z=1: k = x Wk^T; z=2: vT = Wv x^T.
__global__ __launch_bounds__(512) void qkv8(const __bf16* __restrict__ xb,
                                            const __bf16* __restrict__ wq,
                                            const __bf16* __restrict__ wk,
                                            const __bf16* __restrict__ wv,
                                            __bf16* __restrict__ qb,
                                            __bf16* __restrict__ kb,
                                            __bf16* __restrict__ vtb) {
  __shared__ __bf16 sA[4 * 8192];
  __shared__ __bf16 sB[4 * 8192];
  const int raw = blockIdx.x;
  const int wid = (raw & 7) * 24 + (raw >> 3);   // nwg=192, bijective
  const int z = wid >> 6;
  const int r2 = wid & 63;
  const int tid = threadIdx.x;
  const __bf16* A;
  const __bf16* B;
  long row0, col0;
  if (z == 2) {            // A = Wv, B = x  -> vT coalesced
    A = wv; B = xb;
    row0 = (long)(r2 >> 4) * 256;
    col0 = (long)(r2 & 15) * 256;
  } else {
    A = xb; B = (z == 0) ? wq : wk;
    row0 = (long)(r2 >> 2) * 256;
    col0 = (long)(r2 & 3) * 256;
  }
  f32x4 acc[8][4] = {};
  g8_loop<32>(A, 1024, row0, B, 1024, col0, 0, sA, sB, acc, tid);

  const int lane = tid & 63, w = tid >> 6;
  const int wr = w >> 2, wc = w & 3;
  const int lo = lane & 15, hi = lane >> 4;
#pragma unroll
  for (int m = 0; m < 8; ++m)
#pragma unroll
    for (int n = 0; n < 4; ++n)
#pragma unroll
      for (int i = 0; i < 4; ++i) {
        long r = row0 + wr * 128 + m * 16 + hi * 4 + i;
        long c = col0 + wc * 64 + n * 16 + lo;
        __bf16 v = (__bf16)acc[m][n][i];
        if (z == 0)      qb[r * 1024 + c] = v;
        else if (z == 1) kb[r * 1024 + c] = v;
        else             vtb[r * 4096 + c] = v;
      }
}

// sim = q k^T (bf16 out, ld 4096). 1D XCD map.
__global__ __launch_bounds__(512) void qk8(const __bf16* __restrict__ qb,
                                           const __bf16* __restrict__ kb,
                                           __bf16* __restrict__ sim) {
  __shared__ __bf16 sA[4 * 8192];
  __shared__ __bf16 sB[4 * 8192];
  const int raw = blockIdx.x;
  const int wid = (raw & 7) * 32 + (raw >> 3);   // nwg=256, bijective
  const long row0 = (long)(wid >> 4) * 256;
  const long col0 = (long)(wid & 15) * 256;
  const int tid = threadIdx.x;
  f32x4 acc[8][4] = {};
  g8_loop<32>(qb, 1024, row0, kb, 1024, col0, 0, sA, sB, acc, tid);

  const int lane = tid & 63, w = tid >> 6;
  const int wr = w >> 2, wc = w & 3;
  const int lo = lane & 15, hi = lane >> 4;
#pragma unroll
  for (int m = 0; m < 8; ++m)
#pragma unroll
    for (int n = 0; n < 4; ++n)
#pragma unroll
      for (int i = 0; i < 4; ++i) {
        long r = row0 + wr * 128 + m * 16 + hi * 4 + i;
        long c = col0 + wc * 64 + n * 16 + lo;
        sim[r * 4096 + c] = (__bf16)acc[m][n][i];
      }
}

// PV split-K x2: 128x128 tile, 4 waves (2x2 of 64x64), BK=32, NT=64,
// 4-deep, 1 barrier/tile (counted WAITB only).
__global__ __launch_bounds__(256) void pv4(const __bf16* __restrict__ attn,
                                           const __bf16* __restrict__ vt,
                                           float* __restrict__ out,
                                           float* __restrict__ p1) {
  __shared__ __bf16 sA[4 * 4096];
  __shared__ __bf16 sB[4 * 4096];
  const int raw = blockIdx.x;
  const int wid = (raw & 7) * 64 + (raw >> 3);   // nwg=512, bijective
  const int z = wid >> 8;
  const int r2 = wid & 255;
  const long row0 = (long)(r2 >> 3) * 128;
  const long col0 = (long)(r2 & 7) * 128;
  float* C = z ? p1 : out;
  const int kt0 = z * 64;
  const int tid = threadIdx.x;
  const int lane = tid & 63, w = tid >> 6;
  const int wr = w >> 1, wc = w & 1;
  const int lo = lane & 15, hi = lane >> 4;
  constexpr int NT = 64;

  auto stageA = [&](int buf, int kt) {
#pragma unroll
    for (int j = 0; j < 2; ++j) {
      int p = tid + j * 256;
      int row = p >> 2, cg = (p & 3) ^ ((row >> 1) & 3);
      gload_lds16(attn + (row0 + row) * 4096 + kt * 32 + cg * 8,
                  sA + buf * 4096 + p * 8);
    }
  };
  auto stageB = [&](int buf, int kt) {
#pragma unroll
    for (int j = 0; j < 2; ++j) {
      int p = tid + j * 256;
      int row = p >> 2, cg = (p & 3) ^ ((row >> 1) & 3);
      gload_lds16(vt + (col0 + row) * 4096 + kt * 32 + cg * 8,
                  sB + buf * 4096 + p * 8);
    }
  };

  f32x4 acc[4][4] = {};
#pragma unroll
  for (int t = 0; t < 3; ++t) { stageA(t, kt0 + t); stageB(t, kt0 + t); }
  WAITB(8);

  for (int t = 0; t < NT; ++t) {
    const int d = t & 3;
    const __bf16* sAc = sA + d * 4096;
    const __bf16* sBc = sB + d * 4096;
    const int s = (t + 3) & 3;
    bf16x8 af[4], bfr[4];
#pragma unroll
    for (int m = 0; m < 4; ++m) af[m] = LDS_FRAG(sAc, wr * 64 + m * 16 + lo);
#pragma unroll
    for (int n = 0; n < 4; ++n) bfr[n] = LDS_FRAG(sBc, wc * 64 + n * 16 + lo);
    if (t + 3 < NT) { stageA(s, kt0 + t + 3); stageB(s, kt0 + t + 3); }
    // No mid barrier.
    __builtin_amdgcn_s_setprio(1);
#pragma unroll
    for (int m = 0; m < 4; ++m)
#pragma unroll
      for (int n = 0; n < 4; ++n)
        acc[m][n] = MFMA_(af[m], bfr[n], acc[m][n]);
    __builtin_amdgcn_s_setprio(0);
    if (t + 3 < NT)      { WAITB(8); }
    else if (t + 2 < NT) { WAITB(4); }
    else                 { WAITB(0); }
  }

#pragma unroll
  for (int m = 0; m < 4; ++m)
#pragma unroll
    for (int n = 0; n < 4; ++n)
#pragma unroll
      for (int i = 0; i < 4; ++i) {
        long r = row0 + wr * 64 + m * 16 + hi * 4 + i;
        long c = col0 + wc * 64 + n * 16 + lo;
        C[r * 1024 + c] = acc[m][n][i];
      }
}

// out += p1
__global__ __launch_bounds__(256) void reduce_add2(float* __restrict__ out,
                                                   const float* __restrict__ p1) {
  int i = blockIdx.x * 256 + threadIdx.x;
  float4 a = ((const float4*)out)[i];
  float4 b = ((const float4*)p1)[i];
  a.x += b.x; a.y += b.y; a.z += b.z; a.w += b.w;
  ((float4*)out)[i] = a;
}

// One block per row of bf16 sim (ld 4096): mask, stable softmax of row/32.
__global__ __launch_bounds__(256) void softmax_rows(__bf16* __restrict__ sim,
                                                    const int* __restrict__ mask) {
  const int row = blockIdx.x;
  __bf16* rp = sim + (size_t)row * 4096;
  const int4* mrow = (const int4*)(mask + (size_t)row * 4096);
  const int tid = threadIdx.x;

  float vals[16];
  float lmax = -INFINITY;
#pragma unroll
  for (int j = 0; j < 2; ++j) {
    bf16x8 s = ((const bf16x8*)rp)[tid + 256 * j];
    int4 m0 = mrow[(tid + 256 * j) * 2];
    int4 m1 = mrow[(tid + 256 * j) * 2 + 1];
    float f[8];
#pragma unroll
    for (int e = 0; e < 8; ++e) f[e] = (float)s[e];
    f[0] = m0.x ? f[0] : -1e20f;  f[1] = m0.y ? f[1] : -1e20f;
    f[2] = m0.z ? f[2] : -1e20f;  f[3] = m0.w ? f[3] : -1e20f;
    f[4] = m1.x ? f[4] : -1e20f;  f[5] = m1.y ? f[5] : -1e20f;
    f[6] = m1.z ? f[6] : -1e20f;  f[7] = m1.w ? f[7] : -1e20f;
#pragma unroll
    for (int e = 0; e < 8; ++e) {
      vals[8 * j + e] = f[e];
      lmax = fmaxf(lmax, f[e]);
    }
  }
#pragma unroll
  for (int off = 32; off; off >>= 1) lmax = fmaxf(lmax, __shfl_xor(lmax, off));
  __shared__ float red[4];
  __shared__ float bro[2];
  if ((tid & 63) == 0) red[tid >> 6] = lmax;
  __syncthreads();
  if (tid == 0) bro[0] = fmaxf(fmaxf(red[0], red[1]), fmaxf(red[2], red[3]));
  __syncthreads();
  const float m = bro[0];

  float e[16];
  float lsum = 0.f;
#pragma unroll
  for (int j = 0; j < 16; ++j) {
    e[j] = __expf((vals[j] - m) * 0.03125f);
    lsum += e[j];
  }
#pragma unroll
  for (int off = 32; off; off >>= 1) lsum += __shfl_xor(lsum, off);
  if ((tid & 63) == 0) red[tid >> 6] = lsum;
  __syncthreads();
  if (tid == 0) bro[1] = red[0] + red[1] + red[2] + red[3];
  __syncthreads();
  const float inv = 1.0f / bro[1];

#pragma unroll
  for (int j = 0; j < 2; ++j) {
    bf16x8 o;
#pragma unroll
    for (int q = 0; q < 8; ++q) o[q] = (__bf16)(e[8 * j + q] * inv);
    ((bf16x8*)rp)[tid + 256 * j] = o;
  }
}

// Converts x, Wq, Wk, Wv to bf16.
__global__ __launch_bounds__(256) void cvt_all(const float* __restrict__ x,
                                               const float* __restrict__ wq,
                                               const float* __restrict__ wk,
                                               const float* __restrict__ wv,
                                               __bf16* __restrict__ xb,
                                               __bf16* __restrict__ wqb,
                                               __bf16* __restrict__ wkb,
                                               __bf16* __restrict__ wvb) {
  int b = blockIdx.x;
  const float* in;
  __bf16* out;
  int base;
  if (b < 4096)      { in = x;  out = xb;  base = b; }
  else if (b < 5120) { in = wq; out = wqb; base = b - 4096; }
  else if (b < 6144) { in = wk; out = wkb; base = b - 5120; }
  else               { in = wv; out = wvb; base = b - 6144; }
  int i = base * 256 + threadIdx.x;
  float4 f = ((const float4*)in)[i];
  bf16x4 o;
  o[0] = (__bf16)f.x; o[1] = (__bf16)f.y; o[2] = (__bf16)f.z; o[3] = (__bf16)f.w;
  ((bf16x4*)out)[i] = o;
}

extern "C" void kernel_launch(void* const* d_in, const int* in_sizes, int n_in,
                              void* d_out, int out_size, void* d_ws, size_t ws_size,
                              hipStream_t stream) {
  const float* x = (const float*)d_in[0];
  const int* mask = (const int*)d_in[1];
  const float* Wq = (const float*)d_in[2];
  const float* Wk = (const float*)d_in[3];
  const float* Wv = (const float*)d_in[4];
  float* out = (float*)d_out;

  // Workspace layout (70 MB):
  // [0,8M)   vT bf16    [8,16M)  x bf16
  // [16,18M) Wq bf16    [18,20M) Wk bf16   [20,22M) Wv bf16
  // [22,30M) q bf16     [30,38M) k bf16
  // [38,70M) sim bf16 (attn in-place after softmax, ld 4096)
  // PV-time (x,W dead): p1 [8,24M)
  char* ws = (char*)d_ws;
  __bf16* vtb = (__bf16*)(ws);
  __bf16* xb  = (__bf16*)(ws + (8ull << 20));
  __bf16* wqb = (__bf16*)(ws + (16ull << 20));
  __bf16* wkb = (__bf16*)(ws + (18ull << 20));
  __bf16* wvb = (__bf16*)(ws + (20ull << 20));
  __bf16* qb  = (__bf16*)(ws + (22ull << 20));
  __bf16* kb  = (__bf16*)(ws + (30ull << 20));
  __bf16* sim = (__bf16*)(ws + (38ull << 20));
  float*  p1  = (float*)(ws + (8ull << 20));

  cvt_all<<<7168, 256, 0, stream>>>(x, Wq, Wk, Wv, xb, wqb, wkb, wvb);

  // q, k, vT: 192 blocks of 256^2
  qkv8<<<192, 512, 0, stream>>>(xb, wqb, wkb, wvb, qb, kb, vtb);
  // sim = q k^T (4096x4096): 256 blocks
  qk8<<<256, 512, 0, stream>>>(qb, kb, sim);
  // masked stable softmax, normalized attn bf16 in-place
  softmax_rows<<<4096, 256, 0, stream>>>(sim, mask);
  // out = attn vT^T: split-K x2, 512 blocks
  pv4<<<512, 256, 0, stream>>>(sim, vtb, out, p1);
  reduce_add2<<<4096, 256, 0, stream>>>(out, p1);
}